// Round 1
// baseline (449.822 us; speedup 1.0000x reference)
//
#include <hip/hip_runtime.h>
#include <stdint.h>

// ---------------------------------------------------------------------------
// ClusterPolicyNetwork: MHA (fp32) + pairwise task/node MLP (bf16 MFMA)
//
// d_out layout (fp32): matching_scores[1024*1024] | coord_logits[32] | attn_w[1024*1024]
// ---------------------------------------------------------------------------

typedef __attribute__((ext_vector_type(4))) float floatx4;
typedef __attribute__((ext_vector_type(8))) short short8;

// workspace offsets (bytes)
#define OFF_QKV  0x000000u   // 1024*384*4   = 1572864
#define OFF_CTX  0x180000u   // 1024*128*4   = 524288
#define OFF_ATT  0x200000u   // 1024*128*4   = 524288
#define OFF_T1B  0x280000u   // 1024*256*2   = 524288 (bf16, includes +b1)
#define OFF_N1B  0x300000u   // 1024*256*2   = 524288 (bf16)
#define OFF_W2F  0x380000u   // 8*8*64*8*2   = 65536  (bf16 MFMA B-frags)
#define OFF_SM   0x390000u   // 4*1024*4     = 16384  (softmax row max)
#define OFF_SL   0x394000u   // 4*1024*4     = 16384  (softmax row sum)
#define OFF_GS   0x398000u   // 128*4        = 512    (global-state sum)
#define OFF_SC   0x400000u   // 4*1024*1024*4 = 16777216 (raw scores)

// ---- bf16 helpers (pure integer RNE — no hip_bf16.h dependency) ----
__device__ __forceinline__ unsigned bfr(float f) {
    unsigned u = __float_as_uint(f);
    return u + 0x7fffu + ((u >> 16) & 1u);     // rounded bf16 in high 16 bits
}
__device__ __forceinline__ unsigned pack2bf(float a, float b) {
    return (bfr(a) >> 16) | (bfr(b) & 0xffff0000u);
}
__device__ __forceinline__ unsigned short f2bf(float f) {
    return (unsigned short)(bfr(f) >> 16);
}
__device__ __forceinline__ void unpack8bf(uint4 u, float* f) {
    f[0] = __uint_as_float(u.x << 16); f[1] = __uint_as_float(u.x & 0xffff0000u);
    f[2] = __uint_as_float(u.y << 16); f[3] = __uint_as_float(u.y & 0xffff0000u);
    f[4] = __uint_as_float(u.z << 16); f[5] = __uint_as_float(u.z & 0xffff0000u);
    f[6] = __uint_as_float(u.w << 16); f[7] = __uint_as_float(u.w & 0xffff0000u);
}

// ---------------------------------------------------------------------------
// Generic fp32 GEMM: C = scale*(A @ B^T) [+ bias], tile 64x64, 256 threads.
// A [M][lda], B [N][ldb] (weights layout), optional z-strides for batched use.
// ---------------------------------------------------------------------------
template<bool BIAS, bool BF16OUT>
__launch_bounds__(256)
__global__ void gemm_bt(const float* __restrict__ A, int lda, long az,
                        const float* __restrict__ B, int ldb, long bz,
                        const float* __restrict__ bias,
                        void* __restrict__ Cv, int ldc, long cz,
                        int K, float scale)
{
    A += (long)blockIdx.z * az;
    B += (long)blockIdx.z * bz;
    __shared__ float As[16][64];
    __shared__ float Bs[16][64];
    const int tid = threadIdx.x;
    const int m0 = blockIdx.x * 64, n0 = blockIdx.y * 64;
    const int tx = tid & 15, ty = tid >> 4;
    const int lr = tid >> 2;          // staging row 0..63
    const int lk = (tid & 3) * 4;     // staging k offset
    float c[4][4] = {};

    for (int k0 = 0; k0 < K; k0 += 16) {
        float4 a  = *(const float4*)&A[(long)(m0 + lr) * lda + k0 + lk];
        float4 bb = *(const float4*)&B[(long)(n0 + lr) * ldb + k0 + lk];
        __syncthreads();
        As[lk + 0][lr] = a.x;  As[lk + 1][lr] = a.y;  As[lk + 2][lr] = a.z;  As[lk + 3][lr] = a.w;
        Bs[lk + 0][lr] = bb.x; Bs[lk + 1][lr] = bb.y; Bs[lk + 2][lr] = bb.z; Bs[lk + 3][lr] = bb.w;
        __syncthreads();
#pragma unroll
        for (int k = 0; k < 16; k++) {
            float4 av = *(const float4*)&As[k][ty * 4];
            float4 bv = *(const float4*)&Bs[k][tx * 4];
            c[0][0] += av.x * bv.x; c[0][1] += av.x * bv.y; c[0][2] += av.x * bv.z; c[0][3] += av.x * bv.w;
            c[1][0] += av.y * bv.x; c[1][1] += av.y * bv.y; c[1][2] += av.y * bv.z; c[1][3] += av.y * bv.w;
            c[2][0] += av.z * bv.x; c[2][1] += av.z * bv.y; c[2][2] += av.z * bv.z; c[2][3] += av.z * bv.w;
            c[3][0] += av.w * bv.x; c[3][1] += av.w * bv.y; c[3][2] += av.w * bv.z; c[3][3] += av.w * bv.w;
        }
    }

    float bsv[4] = {0.f, 0.f, 0.f, 0.f};
    if (BIAS) {
        float4 t = *(const float4*)&bias[n0 + tx * 4];
        bsv[0] = t.x; bsv[1] = t.y; bsv[2] = t.z; bsv[3] = t.w;
    }
#pragma unroll
    for (int i = 0; i < 4; i++) {
        float v0 = c[i][0] * scale + bsv[0];
        float v1 = c[i][1] * scale + bsv[1];
        float v2 = c[i][2] * scale + bsv[2];
        float v3 = c[i][3] * scale + bsv[3];
        long m = m0 + ty * 4 + i;
        if (BF16OUT) {
            unsigned short* Cp = (unsigned short*)Cv + (long)blockIdx.z * cz;
            ushort4 o;
            o.x = f2bf(v0); o.y = f2bf(v1); o.z = f2bf(v2); o.w = f2bf(v3);
            *(ushort4*)&Cp[m * ldc + n0 + tx * 4] = o;
        } else {
            float* Cp = (float*)Cv + (long)blockIdx.z * cz;
            float4 o = make_float4(v0, v1, v2, v3);
            *(float4*)&Cp[m * ldc + n0 + tx * 4] = o;
        }
    }
}

// ---------------------------------------------------------------------------
// Softmax row stats: m = max, l = sum(exp(s-m)) per (h, q) row of scores.
// ---------------------------------------------------------------------------
__launch_bounds__(256)
__global__ void stats_kernel(const float* __restrict__ sc,
                             float* __restrict__ sm, float* __restrict__ sl)
{
    const int q = blockIdx.x, h = blockIdx.y;
    const float* row = sc + (long)h * 1048576 + (long)q * 1024;
    const int tid = threadIdx.x;
    float4 v = *(const float4*)&row[tid * 4];
    float mx = fmaxf(fmaxf(v.x, v.y), fmaxf(v.z, v.w));
#pragma unroll
    for (int m = 1; m < 64; m <<= 1) mx = fmaxf(mx, __shfl_xor(mx, m));
    __shared__ float redm[4], reds[4];
    const int wv = tid >> 6, ln = tid & 63;
    if (ln == 0) redm[wv] = mx;
    __syncthreads();
    mx = fmaxf(fmaxf(redm[0], redm[1]), fmaxf(redm[2], redm[3]));
    float s = __expf(v.x - mx) + __expf(v.y - mx) + __expf(v.z - mx) + __expf(v.w - mx);
#pragma unroll
    for (int m = 1; m < 64; m <<= 1) s += __shfl_xor(s, m);
    if (ln == 0) reds[wv] = s;
    __syncthreads();
    if (tid == 0) {
        sm[h * 1024 + q] = mx;
        sl[h * 1024 + q] = reds[0] + reds[1] + reds[2] + reds[3];
    }
}

// ---------------------------------------------------------------------------
// attn_w output: mean over heads of normalized softmax.
// ---------------------------------------------------------------------------
__launch_bounds__(256)
__global__ void avg_kernel(const float* __restrict__ sc, const float* __restrict__ sm,
                           const float* __restrict__ sl, float* __restrict__ outw)
{
    const int q = blockIdx.y;
    const int n = blockIdx.x * 256 + threadIdx.x;
    float acc = 0.f;
#pragma unroll
    for (int h = 0; h < 4; h++) {
        float m = sm[h * 1024 + q];
        float il = 1.0f / sl[h * 1024 + q];
        acc += __expf(sc[(long)h * 1048576 + (long)q * 1024 + n] - m) * il;
    }
    outw[(long)q * 1024 + n] = 0.25f * acc;
}

// ---------------------------------------------------------------------------
// ctx = softmax(scores) @ V  (per head). Tile 64q x 32d, K staged 32-wide,
// exp applied on the A-tile load (no normalized-attn materialization).
// ---------------------------------------------------------------------------
__launch_bounds__(256)
__global__ void ctx_kernel(const float* __restrict__ sc, const float* __restrict__ sm,
                           const float* __restrict__ sl, const float* __restrict__ qkv,
                           float* __restrict__ ctx)
{
    const int h = blockIdx.z;
    const int q0 = blockIdx.x * 64;
    __shared__ float As[32][64];
    __shared__ float Vs[32][32];
    const int tid = threadIdx.x;
    const int tx = tid & 15, ty = tid >> 4;
    const int sq = tid >> 3;           // 0..31
    const int sk4 = (tid & 7) * 4;     // 0..28
    float acc[4][2] = {};

    for (int k0 = 0; k0 < 1024; k0 += 32) {
        __syncthreads();
#pragma unroll
        for (int half = 0; half < 2; half++) {
            int q = sq + half * 32;
            float m = sm[h * 1024 + q0 + q];
            float il = 1.0f / sl[h * 1024 + q0 + q];
            float4 s = *(const float4*)&sc[(long)h * 1048576 + (long)(q0 + q) * 1024 + k0 + sk4];
            As[sk4 + 0][q] = __expf(s.x - m) * il;
            As[sk4 + 1][q] = __expf(s.y - m) * il;
            As[sk4 + 2][q] = __expf(s.z - m) * il;
            As[sk4 + 3][q] = __expf(s.w - m) * il;
        }
        {
            float4 v = *(const float4*)&qkv[(long)(k0 + sq) * 384 + 256 + h * 32 + sk4];
            *(float4*)&Vs[sq][sk4] = v;
        }
        __syncthreads();
#pragma unroll
        for (int k = 0; k < 32; k++) {
            float4 a = *(const float4*)&As[k][tx * 4];
            float b0 = Vs[k][ty * 2], b1 = Vs[k][ty * 2 + 1];
            acc[0][0] += a.x * b0; acc[0][1] += a.x * b1;
            acc[1][0] += a.y * b0; acc[1][1] += a.y * b1;
            acc[2][0] += a.z * b0; acc[2][1] += a.z * b1;
            acc[3][0] += a.w * b0; acc[3][1] += a.w * b1;
        }
    }
#pragma unroll
    for (int i = 0; i < 4; i++) {
        float2 o = make_float2(acc[i][0], acc[i][1]);
        *(float2*)&ctx[(long)(q0 + tx * 4 + i) * 128 + h * 32 + ty * 2] = o;
    }
}

// ---------------------------------------------------------------------------
// Column sums of attended (for global mean). 64 blocks x 128 threads.
// ---------------------------------------------------------------------------
__global__ void gsum_kernel(const float* __restrict__ att, float* __restrict__ gs)
{
    const int r0 = blockIdx.x * 16;
    const int t = threadIdx.x;  // 0..127
    float s = 0.f;
#pragma unroll
    for (int r = 0; r < 16; r++) s += att[(long)(r0 + r) * 128 + t];
    atomicAdd(&gs[t], s);
}

// ---------------------------------------------------------------------------
// Coordination head: relu(g @ Wc1^T + bc1) @ Wc2^T + bc2. One block.
// ---------------------------------------------------------------------------
__global__ void coord_kernel(const float* __restrict__ gs,
                             const float* __restrict__ Wc1, const float* __restrict__ bc1,
                             const float* __restrict__ Wc2, const float* __restrict__ bc2,
                             float* __restrict__ out)
{
    __shared__ float g[128];
    __shared__ float hh[256];
    const int t = threadIdx.x;
    if (t < 128) g[t] = gs[t] * (1.0f / 1024.0f);
    __syncthreads();
    {
        float a = bc1[t];
        const float* wr = &Wc1[t * 128];
        for (int d = 0; d < 128; d += 4) {
            float4 w = *(const float4*)&wr[d];
            a += w.x * g[d] + w.y * g[d + 1] + w.z * g[d + 2] + w.w * g[d + 3];
        }
        hh[t] = fmaxf(a, 0.f);
    }
    __syncthreads();
    if (t < 32) {
        float a = bc2[t];
        const float* wr = &Wc2[t * 256];
        for (int c = 0; c < 256; c += 4) {
            float4 w = *(const float4*)&wr[c];
            a += w.x * hh[c] + w.y * hh[c + 1] + w.z * hh[c + 2] + w.w * hh[c + 3];
        }
        out[t] = a;
    }
}

// ---------------------------------------------------------------------------
// W2 -> bf16 MFMA B-fragment layout: w2f[((cc*8+ot)*64+lane)*8 + j]
//   = bf16( W2[ot*16 + (lane&15)][cc*32 + (lane>>4)*8 + j] )
// ---------------------------------------------------------------------------
__global__ void w2prep_kernel(const float* __restrict__ W2, unsigned short* __restrict__ w2f)
{
    const int tid = blockIdx.x * 256 + threadIdx.x;   // 0..4095
    const int lane = tid & 63, frag = tid >> 6;
    const int cc = frag >> 3, ot = frag & 7;
    const int ko = ot * 16 + (lane & 15);
    const int c0 = cc * 32 + (lane >> 4) * 8;
    const float* src = &W2[ko * 256 + c0];
    uint4 o;
    o.x = pack2bf(src[0], src[1]);
    o.y = pack2bf(src[2], src[3]);
    o.z = pack2bf(src[4], src[5]);
    o.w = pack2bf(src[6], src[7]);
    ((uint4*)w2f)[tid] = o;
}

// ---------------------------------------------------------------------------
// THE BIG ONE: matching_scores[t][n] =
//   sigmoid( relu( relu(t1[t]+n1[n]) @ W2^T + b2 ) . W3 + b3 )
// Per wave: 16 n-rows, full ko=128, groups of 4 t. A-frags built in registers
// (n1 resident packed bf16, t1 broadcast loads), W2 frags from LDS.
// ---------------------------------------------------------------------------
__launch_bounds__(256, 2)
__global__ void score_kernel(const unsigned short* __restrict__ t1b,
                             const unsigned short* __restrict__ n1b,
                             const unsigned short* __restrict__ w2f,
                             const float* __restrict__ b2, const float* __restrict__ W3,
                             const float* __restrict__ b3, float* __restrict__ out)
{
    __shared__ unsigned short w2s[32768];   // 64 KB
    const int tid = threadIdx.x;
    const int lane = tid & 63;
    const int wv = tid >> 6;
    const int col = lane & 15;
    const int quad = lane >> 4;
    const int nb = blockIdx.x * 64 + wv * 16;
    const int tb = blockIdx.y * 32;

    // stage W2 fragments -> LDS (coalesced 16B)
    {
        const uint4* src = (const uint4*)w2f;
        uint4* dst = (uint4*)w2s;
#pragma unroll
        for (int i = 0; i < 16; i++) dst[tid + i * 256] = src[tid + i * 256];
    }

    // n1 for this lane's row, all K=256 (packed bf16: 32 VGPRs)
    const int myn = nb + col;
    uint4 n1p[8];
#pragma unroll
    for (int cc = 0; cc < 8; cc++)
        n1p[cc] = *(const uint4*)(n1b + (long)myn * 256 + cc * 32 + quad * 8);

    // per-lane b2/W3 (col -> k = ot*16+col)
    float b2v[8], w3v[8];
#pragma unroll
    for (int ot = 0; ot < 8; ot++) {
        b2v[ot] = b2[ot * 16 + col];
        w3v[ot] = W3[ot * 16 + col];
    }
    const float b3s = b3[0];
    __syncthreads();

    for (int tg = 0; tg < 8; tg++) {
        floatx4 acc[4][8] = {};   // 128 VGPR/AGPR accumulators

#pragma unroll
        for (int cc = 0; cc < 8; cc++) {
            float nf[8];
            unpack8bf(n1p[cc], nf);
            union { unsigned u[4]; short8 s; } af[4];
#pragma unroll
            for (int tt = 0; tt < 4; tt++) {
                const int t = tb + tg * 4 + tt;
                uint4 tp = *(const uint4*)(t1b + (long)t * 256 + cc * 32 + quad * 8);
                float tf[8];
                unpack8bf(tp, tf);
#pragma unroll
                for (int p = 0; p < 4; p++) {
                    float h0 = fmaxf(tf[2 * p] + nf[2 * p], 0.f);
                    float h1 = fmaxf(tf[2 * p + 1] + nf[2 * p + 1], 0.f);
                    af[tt].u[p] = pack2bf(h0, h1);
                }
            }
#pragma unroll
            for (int ot = 0; ot < 8; ot++) {
                short8 bf = *(const short8*)&w2s[((cc * 8 + ot) * 64 + lane) * 8];
#pragma unroll
                for (int tt = 0; tt < 4; tt++)
                    acc[tt][ot] = __builtin_amdgcn_mfma_f32_16x16x32_bf16(af[tt].s, bf, acc[tt][ot], 0, 0, 0);
            }
        }

        // epilogue: h2 = relu(acc + b2); score = sigmoid(h2.W3 + b3)
#pragma unroll
        for (int tt = 0; tt < 4; tt++) {
            const int t = tb + tg * 4 + tt;
            float p0 = 0.f, p1 = 0.f, p2 = 0.f, p3 = 0.f;
#pragma unroll
            for (int ot = 0; ot < 8; ot++) {
                floatx4 a = acc[tt][ot];
                p0 += fmaxf(a[0] + b2v[ot], 0.f) * w3v[ot];
                p1 += fmaxf(a[1] + b2v[ot], 0.f) * w3v[ot];
                p2 += fmaxf(a[2] + b2v[ot], 0.f) * w3v[ot];
                p3 += fmaxf(a[3] + b2v[ot], 0.f) * w3v[ot];
            }
#pragma unroll
            for (int m = 1; m < 16; m <<= 1) {
                p0 += __shfl_xor(p0, m);
                p1 += __shfl_xor(p1, m);
                p2 += __shfl_xor(p2, m);
                p3 += __shfl_xor(p3, m);
            }
            if (col == 0) {
                float4 o;
                o.x = 1.0f / (1.0f + __expf(-(p0 + b3s)));
                o.y = 1.0f / (1.0f + __expf(-(p1 + b3s)));
                o.z = 1.0f / (1.0f + __expf(-(p2 + b3s)));
                o.w = 1.0f / (1.0f + __expf(-(p3 + b3s)));
                *(float4*)&out[(long)t * 1024 + nb + quad * 4] = o;
            }
        }
    }
}

// ---------------------------------------------------------------------------
extern "C" void kernel_launch(void* const* d_in, const int* in_sizes, int n_in,
                              void* d_out, int out_size, void* d_ws, size_t ws_size,
                              hipStream_t stream)
{
    const float* node = (const float*)d_in[0];
    const float* task = (const float*)d_in[1];
    const float* ipw  = (const float*)d_in[2];
    const float* ipb  = (const float*)d_in[3];
    const float* outw = (const float*)d_in[4];
    const float* outb = (const float*)d_in[5];
    const float* W1   = (const float*)d_in[6];
    const float* b1   = (const float*)d_in[7];
    const float* W2   = (const float*)d_in[8];
    const float* b2   = (const float*)d_in[9];
    const float* W3   = (const float*)d_in[10];
    const float* b3   = (const float*)d_in[11];
    const float* Wc1  = (const float*)d_in[12];
    const float* bc1  = (const float*)d_in[13];
    const float* Wc2  = (const float*)d_in[14];
    const float* bc2  = (const float*)d_in[15];

    char* ws = (char*)d_ws;
    float* qkv = (float*)(ws + OFF_QKV);
    float* sc  = (float*)(ws + OFF_SC);
    float* ctx = (float*)(ws + OFF_CTX);
    float* att = (float*)(ws + OFF_ATT);
    unsigned short* t1b = (unsigned short*)(ws + OFF_T1B);
    unsigned short* n1b = (unsigned short*)(ws + OFF_N1B);
    unsigned short* w2f = (unsigned short*)(ws + OFF_W2F);
    float* sm = (float*)(ws + OFF_SM);
    float* sl = (float*)(ws + OFF_SL);
    float* gs = (float*)(ws + OFF_GS);

    float* out_match = (float*)d_out;
    float* out_coord = out_match + 1048576;
    float* out_attn  = out_coord + 32;

    // QKV projection: [1024,128] @ [384,128]^T + b -> qkv [1024,384]
    gemm_bt<true, false><<<dim3(16, 6, 1), 256, 0, stream>>>(
        node, 128, 0, ipw, 128, 0, ipb, qkv, 384, 0, 128, 1.0f);
    // scores[h] = Qh @ Kh^T / sqrt(32) -> sc [4][1024][1024]
    gemm_bt<false, false><<<dim3(16, 16, 4), 256, 0, stream>>>(
        qkv, 384, 32, qkv + 128, 384, 32, nullptr, sc, 1024, 1048576, 32, 0.17677669529663687f);
    // softmax stats per (h,q)
    stats_kernel<<<dim3(1024, 4, 1), 256, 0, stream>>>(sc, sm, sl);
    // attn_w = mean_h softmax
    avg_kernel<<<dim3(4, 1024, 1), 256, 0, stream>>>(sc, sm, sl, out_attn);
    // ctx = softmax @ V
    ctx_kernel<<<dim3(16, 1, 4), 256, 0, stream>>>(sc, sm, sl, qkv, ctx);
    // attended = ctx @ out_w^T + out_b
    gemm_bt<true, false><<<dim3(16, 2, 1), 256, 0, stream>>>(
        ctx, 128, 0, outw, 128, 0, outb, att, 128, 0, 128, 1.0f);
    // global-state column sums
    hipMemsetAsync(gs, 0, 512, stream);
    gsum_kernel<<<dim3(64, 1, 1), 128, 0, stream>>>(att, gs);
    // t1b = bf16(task @ W1[:, :128]^T + b1)
    gemm_bt<true, true><<<dim3(16, 4, 1), 256, 0, stream>>>(
        task, 128, 0, W1, 256, 0, b1, t1b, 256, 0, 128, 1.0f);
    // n1b = bf16(attended @ W1[:, 128:]^T)
    gemm_bt<false, true><<<dim3(16, 4, 1), 256, 0, stream>>>(
        att, 128, 0, W1 + 128, 256, 0, nullptr, n1b, 256, 0, 128, 1.0f);
    // W2 -> MFMA fragment layout
    w2prep_kernel<<<dim3(16, 1, 1), 256, 0, stream>>>(W2, w2f);
    // coordination head
    coord_kernel<<<dim3(1, 1, 1), 256, 0, stream>>>(gs, Wc1, bc1, Wc2, bc2, out_coord);
    // matching scores (the 68.7 GFLOP kernel)
    score_kernel<<<dim3(16, 32, 1), 256, 0, stream>>>(t1b, n1b, w2f, b2, W3, b3, out_match);
}

// Round 2
// 255.496 us; speedup vs baseline: 1.7606x; 1.7606x over previous
//
#include <hip/hip_runtime.h>
#include <hip/hip_fp16.h>
#include <stdint.h>

// ---------------------------------------------------------------------------
// ClusterPolicyNetwork: MHA (fp32) + pairwise task/node MLP (f16 MFMA)
// d_out (fp32): matching_scores[1024*1024] | coord_logits[32] | attn_w[1024*1024]
// ---------------------------------------------------------------------------

typedef __attribute__((ext_vector_type(4))) float floatx4;
typedef __attribute__((ext_vector_type(8))) _Float16 half8;

// workspace offsets (bytes)
#define OFF_QKV  0x000000u   // 1024*384*4   = 1572864
#define OFF_CTX  0x180000u   // 1024*128*4   = 524288
#define OFF_ATT  0x200000u   // 1024*128*4   = 524288
#define OFF_T1H  0x280000u   // 1024*256*2   = 524288 (f16, includes +b1)
#define OFF_N1H  0x300000u   // 1024*256*2   = 524288 (f16)
#define OFF_W2F  0x380000u   // 8*8*64*8*2   = 65536  (f16 MFMA B-frags)
#define OFF_SM   0x390000u   // 4*1024*4
#define OFF_SL   0x394000u   // 4*1024*4
#define OFF_GS   0x398000u   // 128*4
#define OFF_SC   0x400000u   // 4*1024*1024*4 = 16777216 (raw scores)

// ---- packed f16 helpers (VOP3P, guaranteed on gfx950) ----
__device__ __forceinline__ unsigned pkadd(unsigned a, unsigned b) {
    unsigned r; asm("v_pk_add_f16 %0, %1, %2" : "=v"(r) : "v"(a), "v"(b)); return r;
}
__device__ __forceinline__ unsigned pkmax(unsigned a, unsigned b) {
    unsigned r; asm("v_pk_max_f16 %0, %1, %2" : "=v"(r) : "v"(a), "v"(b)); return r;
}
__device__ __forceinline__ unsigned pk2h(float a, float b) {
    return (unsigned)__half_as_ushort(__float2half(a)) |
           ((unsigned)__half_as_ushort(__float2half(b)) << 16);
}

// ---------------------------------------------------------------------------
// Generic fp32 GEMM: C = scale*(A @ B^T) [+ bias], tile 64x64, 256 threads.
// F16OUT: emit __half. COLSUM: also accumulate column sums of C into gsum.
// ---------------------------------------------------------------------------
template<bool BIAS, bool F16OUT, bool COLSUM>
__launch_bounds__(256)
__global__ void gemm_bt(const float* __restrict__ A, int lda, long az,
                        const float* __restrict__ B, int ldb, long bz,
                        const float* __restrict__ bias,
                        void* __restrict__ Cv, int ldc, long cz,
                        int K, float scale, float* __restrict__ gsum)
{
    A += (long)blockIdx.z * az;
    B += (long)blockIdx.z * bz;
    __shared__ float As[16][64];
    __shared__ float Bs[16][64];
    __shared__ float cs[64];
    const int tid = threadIdx.x;
    const int m0 = blockIdx.x * 64, n0 = blockIdx.y * 64;
    const int tx = tid & 15, ty = tid >> 4;
    const int lr = tid >> 2;
    const int lk = (tid & 3) * 4;
    if (COLSUM && tid < 64) cs[tid] = 0.f;
    float c[4][4] = {};

    for (int k0 = 0; k0 < K; k0 += 16) {
        float4 a  = *(const float4*)&A[(long)(m0 + lr) * lda + k0 + lk];
        float4 bb = *(const float4*)&B[(long)(n0 + lr) * ldb + k0 + lk];
        __syncthreads();
        As[lk + 0][lr] = a.x;  As[lk + 1][lr] = a.y;  As[lk + 2][lr] = a.z;  As[lk + 3][lr] = a.w;
        Bs[lk + 0][lr] = bb.x; Bs[lk + 1][lr] = bb.y; Bs[lk + 2][lr] = bb.z; Bs[lk + 3][lr] = bb.w;
        __syncthreads();
#pragma unroll
        for (int k = 0; k < 16; k++) {
            float4 av = *(const float4*)&As[k][ty * 4];
            float4 bv = *(const float4*)&Bs[k][tx * 4];
            c[0][0] += av.x * bv.x; c[0][1] += av.x * bv.y; c[0][2] += av.x * bv.z; c[0][3] += av.x * bv.w;
            c[1][0] += av.y * bv.x; c[1][1] += av.y * bv.y; c[1][2] += av.y * bv.z; c[1][3] += av.y * bv.w;
            c[2][0] += av.z * bv.x; c[2][1] += av.z * bv.y; c[2][2] += av.z * bv.z; c[2][3] += av.z * bv.w;
            c[3][0] += av.w * bv.x; c[3][1] += av.w * bv.y; c[3][2] += av.w * bv.z; c[3][3] += av.w * bv.w;
        }
    }

    float bsv[4] = {0.f, 0.f, 0.f, 0.f};
    if (BIAS) {
        float4 t = *(const float4*)&bias[n0 + tx * 4];
        bsv[0] = t.x; bsv[1] = t.y; bsv[2] = t.z; bsv[3] = t.w;
    }
#pragma unroll
    for (int i = 0; i < 4; i++) {
        float v0 = c[i][0] * scale + bsv[0];
        float v1 = c[i][1] * scale + bsv[1];
        float v2 = c[i][2] * scale + bsv[2];
        float v3 = c[i][3] * scale + bsv[3];
        long m = m0 + ty * 4 + i;
        if (F16OUT) {
            unsigned short* Cp = (unsigned short*)Cv + (long)blockIdx.z * cz;
            ushort4 o;
            o.x = __half_as_ushort(__float2half(v0));
            o.y = __half_as_ushort(__float2half(v1));
            o.z = __half_as_ushort(__float2half(v2));
            o.w = __half_as_ushort(__float2half(v3));
            *(ushort4*)&Cp[m * ldc + n0 + tx * 4] = o;
        } else {
            float* Cp = (float*)Cv + (long)blockIdx.z * cz;
            *(float4*)&Cp[m * ldc + n0 + tx * 4] = make_float4(v0, v1, v2, v3);
        }
        if (COLSUM) {
            atomicAdd(&cs[tx * 4 + 0], v0);
            atomicAdd(&cs[tx * 4 + 1], v1);
            atomicAdd(&cs[tx * 4 + 2], v2);
            atomicAdd(&cs[tx * 4 + 3], v3);
        }
    }
    if (COLSUM) {
        __syncthreads();
        if (tid < 64) atomicAdd(&gsum[n0 + tid], cs[tid]);
    }
}

// ---------------------------------------------------------------------------
// Softmax row stats per (h, q).
// ---------------------------------------------------------------------------
__launch_bounds__(256)
__global__ void stats_kernel(const float* __restrict__ sc,
                             float* __restrict__ sm, float* __restrict__ sl)
{
    const int q = blockIdx.x, h = blockIdx.y;
    const float* row = sc + (long)h * 1048576 + (long)q * 1024;
    const int tid = threadIdx.x;
    float4 v = *(const float4*)&row[tid * 4];
    float mx = fmaxf(fmaxf(v.x, v.y), fmaxf(v.z, v.w));
#pragma unroll
    for (int m = 1; m < 64; m <<= 1) mx = fmaxf(mx, __shfl_xor(mx, m));
    __shared__ float redm[4], reds[4];
    const int wv = tid >> 6, ln = tid & 63;
    if (ln == 0) redm[wv] = mx;
    __syncthreads();
    mx = fmaxf(fmaxf(redm[0], redm[1]), fmaxf(redm[2], redm[3]));
    float s = __expf(v.x - mx) + __expf(v.y - mx) + __expf(v.z - mx) + __expf(v.w - mx);
#pragma unroll
    for (int m = 1; m < 64; m <<= 1) s += __shfl_xor(s, m);
    if (ln == 0) reds[wv] = s;
    __syncthreads();
    if (tid == 0) {
        sm[h * 1024 + q] = mx;
        sl[h * 1024 + q] = reds[0] + reds[1] + reds[2] + reds[3];
    }
}

// ---------------------------------------------------------------------------
// attn_w output: mean over heads of normalized softmax.
// ---------------------------------------------------------------------------
__launch_bounds__(256)
__global__ void avg_kernel(const float* __restrict__ sc, const float* __restrict__ sm,
                           const float* __restrict__ sl, float* __restrict__ outw)
{
    const int q = blockIdx.y;
    const int n = blockIdx.x * 256 + threadIdx.x;
    float acc = 0.f;
#pragma unroll
    for (int h = 0; h < 4; h++) {
        float m = sm[h * 1024 + q];
        float il = 1.0f / sl[h * 1024 + q];
        acc += __expf(sc[(long)h * 1048576 + (long)q * 1024 + n] - m) * il;
    }
    outw[(long)q * 1024 + n] = 0.25f * acc;
}

// ---------------------------------------------------------------------------
// ctx = softmax(scores) @ V, split-k over 8 chunks of 128, fp32 atomicAdd.
// grid (16 qtiles, 8 ksplit, 4 heads)
// ---------------------------------------------------------------------------
__launch_bounds__(256)
__global__ void ctx_kernel(const float* __restrict__ sc, const float* __restrict__ sm,
                           const float* __restrict__ sl, const float* __restrict__ qkv,
                           float* __restrict__ ctx)
{
    const int h = blockIdx.z;
    const int q0 = blockIdx.x * 64;
    const int kbase = blockIdx.y * 128;
    __shared__ float As[32][64];
    __shared__ float Vs[32][32];
    const int tid = threadIdx.x;
    const int tx = tid & 15, ty = tid >> 4;
    const int sq = tid >> 3;
    const int sk4 = (tid & 7) * 4;
    float acc[4][2] = {};

    for (int k0 = kbase; k0 < kbase + 128; k0 += 32) {
        __syncthreads();
#pragma unroll
        for (int half = 0; half < 2; half++) {
            int q = sq + half * 32;
            float m = sm[h * 1024 + q0 + q];
            float il = 1.0f / sl[h * 1024 + q0 + q];
            float4 s = *(const float4*)&sc[(long)h * 1048576 + (long)(q0 + q) * 1024 + k0 + sk4];
            As[sk4 + 0][q] = __expf(s.x - m) * il;
            As[sk4 + 1][q] = __expf(s.y - m) * il;
            As[sk4 + 2][q] = __expf(s.z - m) * il;
            As[sk4 + 3][q] = __expf(s.w - m) * il;
        }
        *(float4*)&Vs[sq][sk4] = *(const float4*)&qkv[(long)(k0 + sq) * 384 + 256 + h * 32 + sk4];
        __syncthreads();
#pragma unroll
        for (int k = 0; k < 32; k++) {
            float4 a = *(const float4*)&As[k][tx * 4];
            float b0 = Vs[k][ty * 2], b1 = Vs[k][ty * 2 + 1];
            acc[0][0] += a.x * b0; acc[0][1] += a.x * b1;
            acc[1][0] += a.y * b0; acc[1][1] += a.y * b1;
            acc[2][0] += a.z * b0; acc[2][1] += a.z * b1;
            acc[3][0] += a.w * b0; acc[3][1] += a.w * b1;
        }
    }
#pragma unroll
    for (int i = 0; i < 4; i++) {
        atomicAdd(&ctx[(long)(q0 + tx * 4 + i) * 128 + h * 32 + ty * 2 + 0], acc[i][0]);
        atomicAdd(&ctx[(long)(q0 + tx * 4 + i) * 128 + h * 32 + ty * 2 + 1], acc[i][1]);
    }
}

// ---------------------------------------------------------------------------
// Coordination head. One block.
// ---------------------------------------------------------------------------
__global__ void coord_kernel(const float* __restrict__ gs,
                             const float* __restrict__ Wc1, const float* __restrict__ bc1,
                             const float* __restrict__ Wc2, const float* __restrict__ bc2,
                             float* __restrict__ out)
{
    __shared__ float g[128];
    __shared__ float hh[256];
    const int t = threadIdx.x;
    if (t < 128) g[t] = gs[t] * (1.0f / 1024.0f);
    __syncthreads();
    {
        float a = bc1[t];
        const float* wr = &Wc1[t * 128];
        for (int d = 0; d < 128; d += 4) {
            float4 w = *(const float4*)&wr[d];
            a += w.x * g[d] + w.y * g[d + 1] + w.z * g[d + 2] + w.w * g[d + 3];
        }
        hh[t] = fmaxf(a, 0.f);
    }
    __syncthreads();
    if (t < 32) {
        float a = bc2[t];
        const float* wr = &Wc2[t * 256];
        for (int c = 0; c < 256; c += 4) {
            float4 w = *(const float4*)&wr[c];
            a += w.x * hh[c] + w.y * hh[c + 1] + w.z * hh[c + 2] + w.w * hh[c + 3];
        }
        out[t] = a;
    }
}

// ---------------------------------------------------------------------------
// W2 -> f16 MFMA B-fragment layout: frag[((cc*8+ot)*64+lane)*8 + j]
//   = f16( W2[ot*16 + (lane&15)][cc*32 + (lane>>4)*8 + j] )
// ---------------------------------------------------------------------------
__global__ void w2prep_kernel(const float* __restrict__ W2, unsigned short* __restrict__ w2f)
{
    const int tid = blockIdx.x * 256 + threadIdx.x;   // 0..4095
    const int lane = tid & 63, frag = tid >> 6;
    const int cc = frag >> 3, ot = frag & 7;
    const int ko = ot * 16 + (lane & 15);
    const int c0 = cc * 32 + (lane >> 4) * 8;
    const float* src = &W2[ko * 256 + c0];
    uint4 o;
    o.x = pk2h(src[0], src[1]);
    o.y = pk2h(src[2], src[3]);
    o.z = pk2h(src[4], src[5]);
    o.w = pk2h(src[6], src[7]);
    ((uint4*)w2f)[tid] = o;
}

// ---------------------------------------------------------------------------
// matching_scores[t][n] = sigmoid(relu(relu(t1+n1) @ W2^T + b2).W3 + b3)
// f16 MFMA. Per wave: 16 n-rows (resident packed f16), 32 t's via LDS-free
// hoisted global loads (L1-resident 16KB), W2 frags in 64KB LDS.
// A-frag build = v_pk_add_f16 + v_pk_max_f16 only.
// ---------------------------------------------------------------------------
__launch_bounds__(256, 2)
__global__ void score_kernel(const unsigned short* __restrict__ t1h,
                             const unsigned short* __restrict__ n1h,
                             const unsigned short* __restrict__ w2f,
                             const float* __restrict__ b2, const float* __restrict__ W3,
                             const float* __restrict__ b3, float* __restrict__ out)
{
    __shared__ unsigned short w2s[32768];   // 64 KB
    const int tid = threadIdx.x;
    const int lane = tid & 63;
    const int wv = tid >> 6;
    const int col = lane & 15;
    const int quad = lane >> 4;
    const int nb = blockIdx.x * 64 + wv * 16;
    const int tb = blockIdx.y * 32;

    // stage W2 fragments -> LDS (coalesced 16B per lane)
    {
        const uint4* src = (const uint4*)w2f;
        uint4* dst = (uint4*)w2s;
#pragma unroll
        for (int i = 0; i < 16; i++) dst[tid + i * 256] = src[tid + i * 256];
    }

    // n1 slice for this lane, all K=256 (packed f16: 32 VGPRs)
    const int myn = nb + col;
    uint4 n1p[8];
#pragma unroll
    for (int cc = 0; cc < 8; cc++)
        n1p[cc] = *(const uint4*)(n1h + (long)myn * 256 + cc * 32 + quad * 8);

    float b2v[8], w3v[8];
#pragma unroll
    for (int ot = 0; ot < 8; ot++) {
        b2v[ot] = b2[ot * 16 + col];
        w3v[ot] = W3[ot * 16 + col];
    }
    const float b3s = b3[0];
    __syncthreads();

    for (int tg = 0; tg < 8; tg++) {
        floatx4 acc[4][8] = {};

#pragma unroll
        for (int cc = 0; cc < 8; cc++) {
            // hoisted t-loads for the 4 t's of this group (independent, L1-hit)
            uint4 tp[4];
#pragma unroll
            for (int tt = 0; tt < 4; tt++)
                tp[tt] = *(const uint4*)(t1h + (long)(tb + tg * 4 + tt) * 256 + cc * 32 + quad * 8);

            const unsigned* npu = (const unsigned*)&n1p[cc];
            union { unsigned u[4]; half8 h; } af[4];
#pragma unroll
            for (int tt = 0; tt < 4; tt++) {
                const unsigned* tpu = (const unsigned*)&tp[tt];
#pragma unroll
                for (int p = 0; p < 4; p++)
                    af[tt].u[p] = pkmax(pkadd(tpu[p], npu[p]), 0u);
            }
#pragma unroll
            for (int ot = 0; ot < 8; ot++) {
                union { uint4 u; half8 h; } bf;
                bf.u = *(const uint4*)&w2s[((cc * 8 + ot) * 64 + lane) * 8];
#pragma unroll
                for (int tt = 0; tt < 4; tt++)
                    acc[tt][ot] = __builtin_amdgcn_mfma_f32_16x16x32_f16(af[tt].h, bf.h, acc[tt][ot], 0, 0, 0);
            }
        }

        // epilogue: h2 = relu(acc + b2); score = sigmoid(h2.W3 + b3)
#pragma unroll
        for (int tt = 0; tt < 4; tt++) {
            const int t = tb + tg * 4 + tt;
            float p0 = 0.f, p1 = 0.f, p2 = 0.f, p3 = 0.f;
#pragma unroll
            for (int ot = 0; ot < 8; ot++) {
                floatx4 a = acc[tt][ot];
                p0 += fmaxf(a[0] + b2v[ot], 0.f) * w3v[ot];
                p1 += fmaxf(a[1] + b2v[ot], 0.f) * w3v[ot];
                p2 += fmaxf(a[2] + b2v[ot], 0.f) * w3v[ot];
                p3 += fmaxf(a[3] + b2v[ot], 0.f) * w3v[ot];
            }
#pragma unroll
            for (int m = 1; m < 16; m <<= 1) {
                p0 += __shfl_xor(p0, m);
                p1 += __shfl_xor(p1, m);
                p2 += __shfl_xor(p2, m);
                p3 += __shfl_xor(p3, m);
            }
            if (col == 0) {
                float4 o;
                o.x = 1.0f / (1.0f + __expf(-(p0 + b3s)));
                o.y = 1.0f / (1.0f + __expf(-(p1 + b3s)));
                o.z = 1.0f / (1.0f + __expf(-(p2 + b3s)));
                o.w = 1.0f / (1.0f + __expf(-(p3 + b3s)));
                *(float4*)&out[(long)t * 1024 + nb + quad * 4] = o;
            }
        }
    }
}

// ---------------------------------------------------------------------------
extern "C" void kernel_launch(void* const* d_in, const int* in_sizes, int n_in,
                              void* d_out, int out_size, void* d_ws, size_t ws_size,
                              hipStream_t stream)
{
    const float* node = (const float*)d_in[0];
    const float* task = (const float*)d_in[1];
    const float* ipw  = (const float*)d_in[2];
    const float* ipb  = (const float*)d_in[3];
    const float* outw = (const float*)d_in[4];
    const float* outb = (const float*)d_in[5];
    const float* W1   = (const float*)d_in[6];
    const float* b1   = (const float*)d_in[7];
    const float* W2   = (const float*)d_in[8];
    const float* b2   = (const float*)d_in[9];
    const float* W3   = (const float*)d_in[10];
    const float* b3   = (const float*)d_in[11];
    const float* Wc1  = (const float*)d_in[12];
    const float* bc1  = (const float*)d_in[13];
    const float* Wc2  = (const float*)d_in[14];
    const float* bc2  = (const float*)d_in[15];

    char* ws = (char*)d_ws;
    float* qkv = (float*)(ws + OFF_QKV);
    float* sc  = (float*)(ws + OFF_SC);
    float* ctx = (float*)(ws + OFF_CTX);
    float* att = (float*)(ws + OFF_ATT);
    unsigned short* t1h = (unsigned short*)(ws + OFF_T1H);
    unsigned short* n1h = (unsigned short*)(ws + OFF_N1H);
    unsigned short* w2f = (unsigned short*)(ws + OFF_W2F);
    float* sm = (float*)(ws + OFF_SM);
    float* sl = (float*)(ws + OFF_SL);
    float* gs = (float*)(ws + OFF_GS);

    float* out_match = (float*)d_out;
    float* out_coord = out_match + 1048576;
    float* out_attn  = out_coord + 32;

    // QKV projection
    gemm_bt<true, false, false><<<dim3(16, 6, 1), 256, 0, stream>>>(
        node, 128, 0, ipw, 128, 0, ipb, qkv, 384, 0, 128, 1.0f, nullptr);
    // scores[h] = Qh @ Kh^T / sqrt(32)
    gemm_bt<false, false, false><<<dim3(16, 16, 4), 256, 0, stream>>>(
        qkv, 384, 32, qkv + 128, 384, 32, nullptr, sc, 1024, 1048576, 32,
        0.17677669529663687f, nullptr);
    // softmax stats
    stats_kernel<<<dim3(1024, 4, 1), 256, 0, stream>>>(sc, sm, sl);
    // attn_w output
    avg_kernel<<<dim3(4, 1024, 1), 256, 0, stream>>>(sc, sm, sl, out_attn);
    // zero ctx + gs, then split-k ctx
    hipMemsetAsync(ctx, 0, 1024 * 128 * 4, stream);
    hipMemsetAsync(gs, 0, 512, stream);
    ctx_kernel<<<dim3(16, 8, 4), 256, 0, stream>>>(sc, sm, sl, qkv, ctx);
    // attended = ctx @ out_w^T + out_b, fused column sums -> gs
    gemm_bt<true, false, true><<<dim3(16, 2, 1), 256, 0, stream>>>(
        ctx, 128, 0, outw, 128, 0, outb, att, 128, 0, 128, 1.0f, gs);
    // t1h = f16(task @ W1[:, :128]^T + b1)
    gemm_bt<true, true, false><<<dim3(16, 4, 1), 256, 0, stream>>>(
        task, 128, 0, W1, 256, 0, b1, t1h, 256, 0, 128, 1.0f, nullptr);
    // n1h = f16(attended @ W1[:, 128:]^T)
    gemm_bt<false, true, false><<<dim3(16, 4, 1), 256, 0, stream>>>(
        att, 128, 0, W1 + 128, 256, 0, nullptr, n1h, 256, 0, 128, 1.0f, nullptr);
    // W2 -> f16 MFMA fragments
    w2prep_kernel<<<dim3(16, 1, 1), 256, 0, stream>>>(W2, w2f);
    // coordination head
    coord_kernel<<<dim3(1, 1, 1), 256, 0, stream>>>(gs, Wc1, bc1, Wc2, bc2, out_coord);
    // matching scores (68.7 GFLOP)
    score_kernel<<<dim3(16, 32, 1), 256, 0, stream>>>(t1h, n1h, w2f, b2, W3, b3, out_match);
}